// Round 5
// baseline (215.285 us; speedup 1.0000x reference)
//
#include <hip/hip_runtime.h>
#include <hip/hip_bf16.h>
#include <math.h>

// B=16, D=128, OUT=128, M runtime (100000).
// v5 = v1's exact kB structure (measured 59us, 84 VGPR, no spill) + proven deltas:
//   - relu-split scores: relu(x)=(x+|x|)/2; sm0/sm1 hoisted (b-invariant);
//     per-b const dropped (softmax shift-inv; cancels exactly in acc/lsum);
//     0.5 folded into register w2q. 2 ops/term vs 3. b-loop stays UNROLLED,
//     2 m-tiles/wave for ILP (v4 lesson: rolled loop + 1 chain => latency-bound).
//   - pool -> fp32 atomicAdd (kC1 + pacc round-trip deleted; verified v3/v4)
//   - kDiv folded into kB via atomic-counter finisher (3 -> 2 launches;
//     ~25us/launch overhead measured across v1-v4). Coherent reads via
//     atomicAdd(p, 0.f); counter zeroed by kA each replay.
// kA: blocks 0-63 w1b=bf16(W1 node half); 64-71 anchor GEMM; 72 zero acc+counter

typedef __attribute__((ext_vector_type(8))) short bf16x8;
typedef __attribute__((ext_vector_type(4))) float f32x4;

__device__ __forceinline__ short f2bs(float f) {
    __hip_bfloat16 h = __float2bfloat16(f);
    return *reinterpret_cast<short*>(&h);
}
__device__ __forceinline__ float bs2f(ushort u) {
    union { unsigned int i; float f; } v; v.i = ((unsigned)u) << 16; return v.f;
}

__global__ __launch_bounds__(256) void kA(const float* __restrict__ W1,
                                          const float* __restrict__ xx,
                                          ushort* __restrict__ w1b,
                                          float* __restrict__ A,
                                          float* __restrict__ acc_g,
                                          float* __restrict__ lsum_acc,
                                          int* __restrict__ counter) {
    const int bi = blockIdx.x, t = threadIdx.x;
    if (bi < 64) {
        int idx = bi * 256 + t;              // 16384 = 128o * 128d
        int o = idx >> 7, d = idx & 127;
        w1b[idx] = (ushort)f2bs(W1[o * 256 + 128 + d]);
        return;
    }
    if (bi == 72) {                          // zero fp32 accumulators + counter
        for (int i = t; i < 2064; i += 256) {
            if (i < 2048) acc_g[i] = 0.f;
            else          lsum_acc[i - 2048] = 0.f;
        }
        if (t == 0) *counter = 0;
        return;
    }
    __shared__ float xxs[16 * 132];
    __shared__ float w1s[16 * 132];
    const int og0 = (bi - 64) * 16;
#pragma unroll
    for (int i = 0; i < 2; ++i) {
        int idx = t + 256 * i;               // 512 float4 = 16 rows * 32
        int r = idx >> 5, c4 = (idx & 31) << 2;
        *(float4*)&xxs[r * 132 + c4] = *(const float4*)&xx[r * 128 + c4];
        *(float4*)&w1s[r * 132 + c4] = *(const float4*)&W1[(og0 + r) * 256 + c4];
    }
    __syncthreads();
    const int ol = t >> 4, b = t & 15;
    float acc = 0.f;
#pragma unroll
    for (int d4 = 0; d4 < 32; ++d4) {
        float4 xv = *(float4*)&xxs[b * 132 + d4 * 4];
        float4 wv = *(float4*)&w1s[ol * 132 + d4 * 4];
        acc += xv.x * wv.x + xv.y * wv.y + xv.z * wv.z + xv.w * wv.w;
    }
    A[b * 128 + og0 + ol] = acc;
}

__global__ __launch_bounds__(256, 3) void kB(
    const float* __restrict__ in, const ushort* __restrict__ w1b,
    const float* __restrict__ W2, const float* __restrict__ A,
    float* __restrict__ acc_g, float* __restrict__ lsum_acc,
    int* __restrict__ counter, float* __restrict__ out, int M, int nb) {
    __shared__ ushort ins[128 * 136];  // bf16 in-tile [m][d]
    __shared__ float As[16 * 128];     // A[b][o]
    __shared__ ushort pb[16 * 136];    // p bf16 [b][m(128)+pad]

    const int tid = threadIdx.x, bid = blockIdx.x;
    const int m0 = bid * 128;
    const int w = tid >> 6, lane = tid & 63;
    const int c = lane & 15, q = lane >> 4;
    const int lim = (M - m0 < 128) ? (M - m0) : 128;

    // ---- stage input tile -> LDS as bf16 ----
#pragma unroll
    for (int i = 0; i < 16; ++i) {
        int idx = tid + 256 * i;              // 4096 float4s = 128 rows * 32
        int r = idx >> 5, c4 = (idx & 31) << 2;
        float4 v = make_float4(0.f, 0.f, 0.f, 0.f);
        if (r < lim) v = *(const float4*)&in[(size_t)(m0 + r) * 128 + c4];
        ushort4 u;
        u.x = (ushort)f2bs(v.x); u.y = (ushort)f2bs(v.y);
        u.z = (ushort)f2bs(v.z); u.w = (ushort)f2bs(v.w);
        *(ushort4*)&ins[r * 136 + c4] = u;
    }
#pragma unroll
    for (int i = 0; i < 2; ++i) {
        int idx = tid + 256 * i;              // 512 float4 = 2048 floats
        *(float4*)&As[idx * 4] = *(const float4*)&A[idx * 4];
    }
    __syncthreads();

    // ---- np^T via MFMA: wave w covers m = w*32 + mt*16 + c, mt in {0,1} ----
    const int mbase = w * 32 + c;
    f32x4 acc[2][8];
#pragma unroll
    for (int mt = 0; mt < 2; ++mt)
#pragma unroll
        for (int ot = 0; ot < 8; ++ot) acc[mt][ot] = (f32x4){0.f, 0.f, 0.f, 0.f};
#pragma unroll
    for (int kb = 0; kb < 4; ++kb) {
        bf16x8 bv0 = *(const bf16x8*)&ins[mbase * 136 + kb * 32 + q * 8];
        bf16x8 bv1 = *(const bf16x8*)&ins[(mbase + 16) * 136 + kb * 32 + q * 8];
#pragma unroll
        for (int ot = 0; ot < 8; ++ot) {
            bf16x8 av = *(const bf16x8*)(w1b + (ot * 16 + c) * 128 + kb * 32 + q * 8);
            acc[0][ot] = __builtin_amdgcn_mfma_f32_16x16x32_bf16(av, bv0, acc[0][ot], 0, 0, 0);
            acc[1][ot] = __builtin_amdgcn_mfma_f32_16x16x32_bf16(av, bv1, acc[1][ot], 0, 0, 0);
        }
    }
    // acc[mt][ot][r] = np[m = w*32 + mt*16 + c][o = ot*16 + q*4 + r]

    // ---- per-lane w2 quads, pre-scaled by 0.5 (relu-split) ----
    f32x4 w2q[8];
#pragma unroll
    for (int ot = 0; ot < 8; ++ot) {
        f32x4 wv = *(const f32x4*)&W2[ot * 16 + q * 4];
        w2q[ot] = wv * 0.5f;
    }

    // ---- sm = 0.5*Sum_o np*w2 per m-tile (b-invariant, hoisted) ----
    float sm0 = 0.f, sm1 = 0.f;
#pragma unroll
    for (int ot = 0; ot < 8; ++ot)
#pragma unroll
        for (int r = 0; r < 4; ++r) {
            sm0 += acc[0][ot][r] * w2q[ot][r];
            sm1 += acc[1][ot][r] * w2q[ot][r];
        }

    // ---- scores: s(b,m) = sm + 0.5*Sum_o |np+A|*w2 (per-b const dropped) ----
    const bool mv0 = (w * 32 + c) < lim;
    const bool mv1 = (w * 32 + 16 + c) < lim;
#pragma unroll
    for (int b = 0; b < 16; ++b) {
        float sa0 = sm0, sa1 = sm1;
#pragma unroll
        for (int ot = 0; ot < 8; ++ot) {
            f32x4 aq = *(f32x4*)&As[b * 128 + ot * 16 + q * 4];  // 16-lane broadcast
#pragma unroll
            for (int r = 0; r < 4; ++r) {
                sa0 += fabsf(acc[0][ot][r] + aq[r]) * w2q[ot][r];  // abs = free modifier
                sa1 += fabsf(acc[1][ot][r] + aq[r]) * w2q[ot][r];
            }
        }
        sa0 += __shfl_xor(sa0, 16, 64);
        sa0 += __shfl_xor(sa0, 32, 64);
        sa1 += __shfl_xor(sa1, 16, 64);
        sa1 += __shfl_xor(sa1, 32, 64);
        if (q == (b & 3)) {
            pb[b * 136 + w * 32 + c]      = (ushort)f2bs(mv0 ? __expf(sa0) : 0.f);
            pb[b * 136 + w * 32 + 16 + c] = (ushort)f2bs(mv1 ? __expf(sa1) : 0.f);
        }
    }
    __syncthreads();

    // ---- pool via MFMA: D = P[16b x 128m] . in[128m x 128d]; wave owns 32 d ----
    f32x4 pd[2];
    pd[0] = (f32x4){0.f, 0.f, 0.f, 0.f};
    pd[1] = (f32x4){0.f, 0.f, 0.f, 0.f};
#pragma unroll
    for (int ks = 0; ks < 4; ++ks) {
        bf16x8 pf = *(const bf16x8*)&pb[c * 136 + ks * 32 + q * 8];  // A-frag P[b=c][k]
#pragma unroll
        for (int t = 0; t < 2; ++t) {
            const int dloc = w * 32 + t * 16 + c;
            bf16x8 bf;
#pragma unroll
            for (int j = 0; j < 8; ++j)
                bf[j] = (short)ins[(ks * 32 + q * 8 + j) * 136 + dloc];
            pd[t] = __builtin_amdgcn_mfma_f32_16x16x32_bf16(pf, bf, pd[t], 0, 0, 0);
        }
    }
    // pd[t][r] = pool[b = q*4+r][d = w*32 + t*16 + c]
#pragma unroll
    for (int t = 0; t < 2; ++t)
#pragma unroll
        for (int r = 0; r < 4; ++r)
            atomicAdd(&acc_g[(q * 4 + r) * 128 + w * 32 + t * 16 + c], pd[t][r]);

    // ---- block lsum from pb: thread (b = tid>>4, jj = tid&15) covers 8 m ----
    {
        const int bb = tid >> 4, jj = tid & 15;
        const ushort* pr = &pb[bb * 136 + jj * 8];
        float part = 0.f;
#pragma unroll
        for (int j2 = 0; j2 < 8; ++j2) part += bs2f(pr[j2]);
#pragma unroll
        for (int off = 1; off < 16; off <<= 1) part += __shfl_xor(part, off, 64);
        if (jj == 0) atomicAdd(&lsum_acc[bb], part);
    }

    // ---- finisher: last block divides and writes out (saves a launch) ----
    __threadfence();
    __shared__ int isLast;
    if (tid == 0) isLast = (atomicAdd(counter, 1) == nb - 1);
    __syncthreads();
    if (isLast) {
        for (int i = tid; i < 2048; i += 256) {
            float a = atomicAdd(&acc_g[i], 0.f);       // coherent read (bypass L1)
            float l = atomicAdd(&lsum_acc[i >> 7], 0.f);
            out[i] = a / l;
        }
    }
}

extern "C" void kernel_launch(void* const* d_in, const int* in_sizes, int n_in,
                              void* d_out, int out_size, void* d_ws, size_t ws_size,
                              hipStream_t stream) {
    const float* xx = (const float*)d_in[0];
    const float* in = (const float*)d_in[1];
    // d_in[2] = adj, unused
    const float* W1 = (const float*)d_in[3];
    const float* W2 = (const float*)d_in[4];
    float* out = (float*)d_out;

    const int M = in_sizes[1] / 128;
    const int nb = (M + 127) / 128;

    float* ws = (float*)d_ws;
    float* A        = ws;                        // 2048 floats
    float* acc_g    = ws + 2048;                 // 2048
    float* lsum_acc = ws + 4096;                 // 16
    int*   counter  = (int*)(ws + 4112);         // 1
    ushort* w1b     = (ushort*)(ws + 4116);      // byte off 16464 = 16*1029, aligned

    kA <<<73, 256, 0, stream>>>(W1, xx, w1b, A, acc_g, lsum_acc, counter);
    kB <<<nb, 256, 0, stream>>>(in, w1b, W2, A, acc_g, lsum_acc, counter, out, M, nb);
}

// Round 6
// 188.593 us; speedup vs baseline: 1.1415x; 1.1415x over previous
//
#include <hip/hip_runtime.h>
#include <hip/hip_bf16.h>
#include <math.h>

// B=16, D=128, OUT=128, M runtime (100000).
// v6 = v5 with ONE change: pool atomics spread over 16 replica accumulators.
//   v5 lesson: 782 blocks atomically adding into the SAME 2048 fp32 addresses
//   (128 lines) serialize ~12.5K RMWs/line at the device coherence point ->
//   +80us stall (VALUBusy 30->10%). rep = bid&15 cuts per-line depth 16x.
//   Finisher sums replicas with verified atomicAdd(p,0.f) coherent reads.
// Carried (all HW-verified): v1 kB structure (2 m-tiles/wave, unrolled b-loop,
//   84 VGPR no-spill), relu-split scores (2 ops/term, sm hoisted, per-b const
//   dropped -- softmax shift-invariant), counter finisher (2 launches).
// NOTE: total = kB + ~70-76us fixed harness constant regardless of launch count
//   (measured v1-v5) -> only kB duration matters.

typedef __attribute__((ext_vector_type(8))) short bf16x8;
typedef __attribute__((ext_vector_type(4))) float f32x4;

#define NREP 16

__device__ __forceinline__ short f2bs(float f) {
    __hip_bfloat16 h = __float2bfloat16(f);
    return *reinterpret_cast<short*>(&h);
}
__device__ __forceinline__ float bs2f(ushort u) {
    union { unsigned int i; float f; } v; v.i = ((unsigned)u) << 16; return v.f;
}

__global__ __launch_bounds__(256) void kA(const float* __restrict__ W1,
                                          const float* __restrict__ xx,
                                          ushort* __restrict__ w1b,
                                          float* __restrict__ A,
                                          float* __restrict__ acc_r,
                                          float* __restrict__ lsum_r,
                                          int* __restrict__ counter) {
    const int bi = blockIdx.x, t = threadIdx.x;
    if (bi < 64) {
        int idx = bi * 256 + t;              // 16384 = 128o * 128d
        int o = idx >> 7, d = idx & 127;
        w1b[idx] = (ushort)f2bs(W1[o * 256 + 128 + d]);
        return;
    }
    if (bi >= 72) {                          // blocks 72-79: zero replica accs
        const int z = bi - 72;               // 4096 floats each = 4 float4/thread
#pragma unroll
        for (int i = 0; i < 4; ++i) {
            int idx = (z * 4096 + t * 4 + i * 1024);
            *(float4*)&acc_r[idx] = make_float4(0.f, 0.f, 0.f, 0.f);
        }
        if (z == 0) {
            if (t < NREP * 16) lsum_r[t] = 0.f;
            if (t == 0) *counter = 0;
        }
        return;
    }
    __shared__ float xxs[16 * 132];
    __shared__ float w1s[16 * 132];
    const int og0 = (bi - 64) * 16;
#pragma unroll
    for (int i = 0; i < 2; ++i) {
        int idx = t + 256 * i;               // 512 float4 = 16 rows * 32
        int r = idx >> 5, c4 = (idx & 31) << 2;
        *(float4*)&xxs[r * 132 + c4] = *(const float4*)&xx[r * 128 + c4];
        *(float4*)&w1s[r * 132 + c4] = *(const float4*)&W1[(og0 + r) * 256 + c4];
    }
    __syncthreads();
    const int ol = t >> 4, b = t & 15;
    float acc = 0.f;
#pragma unroll
    for (int d4 = 0; d4 < 32; ++d4) {
        float4 xv = *(float4*)&xxs[b * 132 + d4 * 4];
        float4 wv = *(float4*)&w1s[ol * 132 + d4 * 4];
        acc += xv.x * wv.x + xv.y * wv.y + xv.z * wv.z + xv.w * wv.w;
    }
    A[b * 128 + og0 + ol] = acc;
}

__global__ __launch_bounds__(256, 3) void kB(
    const float* __restrict__ in, const ushort* __restrict__ w1b,
    const float* __restrict__ W2, const float* __restrict__ A,
    float* __restrict__ acc_r, float* __restrict__ lsum_r,
    int* __restrict__ counter, float* __restrict__ out, int M, int nb) {
    __shared__ ushort ins[128 * 136];  // bf16 in-tile [m][d]
    __shared__ float As[16 * 128];     // A[b][o]
    __shared__ ushort pb[16 * 136];    // p bf16 [b][m(128)+pad]

    const int tid = threadIdx.x, bid = blockIdx.x;
    const int m0 = bid * 128;
    const int w = tid >> 6, lane = tid & 63;
    const int c = lane & 15, q = lane >> 4;
    const int lim = (M - m0 < 128) ? (M - m0) : 128;
    float* __restrict__ accb = acc_r + (size_t)(bid & (NREP - 1)) * 2048;

    // ---- stage input tile -> LDS as bf16 ----
#pragma unroll
    for (int i = 0; i < 16; ++i) {
        int idx = tid + 256 * i;              // 4096 float4s = 128 rows * 32
        int r = idx >> 5, c4 = (idx & 31) << 2;
        float4 v = make_float4(0.f, 0.f, 0.f, 0.f);
        if (r < lim) v = *(const float4*)&in[(size_t)(m0 + r) * 128 + c4];
        ushort4 u;
        u.x = (ushort)f2bs(v.x); u.y = (ushort)f2bs(v.y);
        u.z = (ushort)f2bs(v.z); u.w = (ushort)f2bs(v.w);
        *(ushort4*)&ins[r * 136 + c4] = u;
    }
#pragma unroll
    for (int i = 0; i < 2; ++i) {
        int idx = tid + 256 * i;              // 512 float4 = 2048 floats
        *(float4*)&As[idx * 4] = *(const float4*)&A[idx * 4];
    }
    __syncthreads();

    // ---- np^T via MFMA: wave w covers m = w*32 + mt*16 + c, mt in {0,1} ----
    const int mbase = w * 32 + c;
    f32x4 acc[2][8];
#pragma unroll
    for (int mt = 0; mt < 2; ++mt)
#pragma unroll
        for (int ot = 0; ot < 8; ++ot) acc[mt][ot] = (f32x4){0.f, 0.f, 0.f, 0.f};
#pragma unroll
    for (int kb = 0; kb < 4; ++kb) {
        bf16x8 bv0 = *(const bf16x8*)&ins[mbase * 136 + kb * 32 + q * 8];
        bf16x8 bv1 = *(const bf16x8*)&ins[(mbase + 16) * 136 + kb * 32 + q * 8];
#pragma unroll
        for (int ot = 0; ot < 8; ++ot) {
            bf16x8 av = *(const bf16x8*)(w1b + (ot * 16 + c) * 128 + kb * 32 + q * 8);
            acc[0][ot] = __builtin_amdgcn_mfma_f32_16x16x32_bf16(av, bv0, acc[0][ot], 0, 0, 0);
            acc[1][ot] = __builtin_amdgcn_mfma_f32_16x16x32_bf16(av, bv1, acc[1][ot], 0, 0, 0);
        }
    }
    // acc[mt][ot][r] = np[m = w*32 + mt*16 + c][o = ot*16 + q*4 + r]

    // ---- per-lane w2 quads, pre-scaled by 0.5 (relu-split) ----
    f32x4 w2q[8];
#pragma unroll
    for (int ot = 0; ot < 8; ++ot) {
        f32x4 wv = *(const f32x4*)&W2[ot * 16 + q * 4];
        w2q[ot] = wv * 0.5f;
    }

    // ---- sm = 0.5*Sum_o np*w2 per m-tile (b-invariant, hoisted) ----
    float sm0 = 0.f, sm1 = 0.f;
#pragma unroll
    for (int ot = 0; ot < 8; ++ot)
#pragma unroll
        for (int r = 0; r < 4; ++r) {
            sm0 += acc[0][ot][r] * w2q[ot][r];
            sm1 += acc[1][ot][r] * w2q[ot][r];
        }

    // ---- scores: s(b,m) = sm + 0.5*Sum_o |np+A|*w2 (per-b const dropped) ----
    const bool mv0 = (w * 32 + c) < lim;
    const bool mv1 = (w * 32 + 16 + c) < lim;
#pragma unroll
    for (int b = 0; b < 16; ++b) {
        float sa0 = sm0, sa1 = sm1;
#pragma unroll
        for (int ot = 0; ot < 8; ++ot) {
            f32x4 aq = *(f32x4*)&As[b * 128 + ot * 16 + q * 4];  // 16-lane broadcast
#pragma unroll
            for (int r = 0; r < 4; ++r) {
                sa0 += fabsf(acc[0][ot][r] + aq[r]) * w2q[ot][r];  // abs = free modifier
                sa1 += fabsf(acc[1][ot][r] + aq[r]) * w2q[ot][r];
            }
        }
        sa0 += __shfl_xor(sa0, 16, 64);
        sa0 += __shfl_xor(sa0, 32, 64);
        sa1 += __shfl_xor(sa1, 16, 64);
        sa1 += __shfl_xor(sa1, 32, 64);
        if (q == (b & 3)) {
            pb[b * 136 + w * 32 + c]      = (ushort)f2bs(mv0 ? __expf(sa0) : 0.f);
            pb[b * 136 + w * 32 + 16 + c] = (ushort)f2bs(mv1 ? __expf(sa1) : 0.f);
        }
    }
    __syncthreads();

    // ---- pool via MFMA: D = P[16b x 128m] . in[128m x 128d]; wave owns 32 d ----
    f32x4 pd[2];
    pd[0] = (f32x4){0.f, 0.f, 0.f, 0.f};
    pd[1] = (f32x4){0.f, 0.f, 0.f, 0.f};
#pragma unroll
    for (int ks = 0; ks < 4; ++ks) {
        bf16x8 pf = *(const bf16x8*)&pb[c * 136 + ks * 32 + q * 8];  // A-frag P[b=c][k]
#pragma unroll
        for (int t = 0; t < 2; ++t) {
            const int dloc = w * 32 + t * 16 + c;
            bf16x8 bf;
#pragma unroll
            for (int j = 0; j < 8; ++j)
                bf[j] = (short)ins[(ks * 32 + q * 8 + j) * 136 + dloc];
            pd[t] = __builtin_amdgcn_mfma_f32_16x16x32_bf16(pf, bf, pd[t], 0, 0, 0);
        }
    }
    // pd[t][r] = pool[b = q*4+r][d = w*32 + t*16 + c] -> replica accumulator
#pragma unroll
    for (int t = 0; t < 2; ++t)
#pragma unroll
        for (int r = 0; r < 4; ++r)
            atomicAdd(&accb[(q * 4 + r) * 128 + w * 32 + t * 16 + c], pd[t][r]);

    // ---- block lsum from pb: thread (b = tid>>4, jj = tid&15) covers 8 m ----
    {
        const int bb = tid >> 4, jj = tid & 15;
        const ushort* pr = &pb[bb * 136 + jj * 8];
        float part = 0.f;
#pragma unroll
        for (int j2 = 0; j2 < 8; ++j2) part += bs2f(pr[j2]);
#pragma unroll
        for (int off = 1; off < 16; off <<= 1) part += __shfl_xor(part, off, 64);
        if (jj == 0) atomicAdd(&lsum_r[(bid & (NREP - 1)) * 16 + bb], part);
    }

    // ---- finisher: last block sums replicas, divides, writes out ----
    __threadfence();
    __shared__ int isLast;
    __shared__ float ls[16];
    if (tid == 0) isLast = (atomicAdd(counter, 1) == nb - 1);
    __syncthreads();
    if (isLast) {
        if (tid < 16) {
            float l = 0.f;
#pragma unroll
            for (int rp = 0; rp < NREP; ++rp)
                l += atomicAdd(&lsum_r[rp * 16 + tid], 0.f);   // coherent read
            ls[tid] = l;
        }
        __syncthreads();
        for (int i = tid; i < 2048; i += 256) {
            float a = 0.f;
#pragma unroll
            for (int rp = 0; rp < NREP; ++rp)
                a += atomicAdd(&acc_r[rp * 2048 + i], 0.f);    // coherent read
            out[i] = a / ls[i >> 7];
        }
    }
}

extern "C" void kernel_launch(void* const* d_in, const int* in_sizes, int n_in,
                              void* d_out, int out_size, void* d_ws, size_t ws_size,
                              hipStream_t stream) {
    const float* xx = (const float*)d_in[0];
    const float* in = (const float*)d_in[1];
    // d_in[2] = adj, unused
    const float* W1 = (const float*)d_in[3];
    const float* W2 = (const float*)d_in[4];
    float* out = (float*)d_out;

    const int M = in_sizes[1] / 128;
    const int nb = (M + 127) / 128;

    float* ws = (float*)d_ws;
    float* A       = ws;                         // 2048 floats
    float* acc_r   = ws + 2048;                  // 16*2048 = 32768
    float* lsum_r  = ws + 2048 + 32768;          // 16*16 = 256
    int*   counter = (int*)(ws + 35072);         // 1 (+15 pad)
    ushort* w1b    = (ushort*)(ws + 35088);      // byte 140352, 16B aligned

    kA <<<80, 256, 0, stream>>>(W1, xx, w1b, A, acc_r, lsum_r, counter);
    kB <<<nb, 256, 0, stream>>>(in, w1b, W2, A, acc_r, lsum_r, counter, out, M, nb);
}

// Round 7
// 160.184 us; speedup vs baseline: 1.3440x; 1.1774x over previous
//
#include <hip/hip_runtime.h>
#include <hip/hip_bf16.h>
#include <math.h>

// B=16, D=128, OUT=128, M runtime (100000).
// v7 = v1's proven plain-store pipeline (atomic/fence design abandoned: v5/v6
//   measured +54..79us vs plain stores) + two deltas:
//   1. relu-split scores (verified v2-v6): s = sm + 0.5*Sum|np+A|*w2, per-b
//      const dropped (softmax shift-inv), 0.5 folded into w2q. -20% VALU.
//   2. staging folded into np-phase: global fp32 -> cvt in reg -> {MFMA operand
//      + ds_write_b128 to ins}. Removes staging loop, 8 ds_read_b128, and the
//      load->LDS->read chain; loads feed MFMA directly.
// kB output: plain bf16 pacc + lsum_g stores (v1-proven). kC2 = merged
// reduce+divide (one launch saved; ~5us/launch measured v1-v6).

typedef __attribute__((ext_vector_type(8))) short bf16x8;
typedef __attribute__((ext_vector_type(4))) float f32x4;

__device__ __forceinline__ short f2bs(float f) {
    __hip_bfloat16 h = __float2bfloat16(f);
    return *reinterpret_cast<short*>(&h);
}
__device__ __forceinline__ float bs2f(ushort u) {
    union { unsigned int i; float f; } v; v.i = ((unsigned)u) << 16; return v.f;
}
__device__ __forceinline__ bf16x8 pack8(float4 a, float4 b) {
    bf16x8 r;
    r[0] = f2bs(a.x); r[1] = f2bs(a.y); r[2] = f2bs(a.z); r[3] = f2bs(a.w);
    r[4] = f2bs(b.x); r[5] = f2bs(b.y); r[6] = f2bs(b.z); r[7] = f2bs(b.w);
    return r;
}

__global__ __launch_bounds__(256) void kA(const float* __restrict__ W1,
                                          const float* __restrict__ xx,
                                          ushort* __restrict__ w1b,
                                          float* __restrict__ A) {
    const int bi = blockIdx.x, t = threadIdx.x;
    if (bi < 64) {
        int idx = bi * 256 + t;              // 16384 = 128o * 128d
        int o = idx >> 7, d = idx & 127;
        w1b[idx] = (ushort)f2bs(W1[o * 256 + 128 + d]);
        return;
    }
    __shared__ float xxs[16 * 132];
    __shared__ float w1s[16 * 132];
    const int og0 = (bi - 64) * 16;
#pragma unroll
    for (int i = 0; i < 2; ++i) {
        int idx = t + 256 * i;               // 512 float4 = 16 rows * 32
        int r = idx >> 5, c4 = (idx & 31) << 2;
        *(float4*)&xxs[r * 132 + c4] = *(const float4*)&xx[r * 128 + c4];
        *(float4*)&w1s[r * 132 + c4] = *(const float4*)&W1[(og0 + r) * 256 + c4];
    }
    __syncthreads();
    const int ol = t >> 4, b = t & 15;
    float acc = 0.f;
#pragma unroll
    for (int d4 = 0; d4 < 32; ++d4) {
        float4 xv = *(float4*)&xxs[b * 132 + d4 * 4];
        float4 wv = *(float4*)&w1s[ol * 132 + d4 * 4];
        acc += xv.x * wv.x + xv.y * wv.y + xv.z * wv.z + xv.w * wv.w;
    }
    A[b * 128 + og0 + ol] = acc;
}

__global__ __launch_bounds__(256, 3) void kB(
    const float* __restrict__ in, const ushort* __restrict__ w1b,
    const float* __restrict__ W2, const float* __restrict__ A,
    float* __restrict__ lsum_g, ushort* __restrict__ pacc, int M) {
    __shared__ ushort ins[128 * 136];  // bf16 in-tile [m][d]
    __shared__ float As[16 * 128];     // A[b][o]
    __shared__ ushort pb[16 * 136];    // p bf16 [b][m(128)+pad]

    const int tid = threadIdx.x, bid = blockIdx.x;
    const int m0 = bid * 128;
    const int w = tid >> 6, lane = tid & 63;
    const int c = lane & 15, q = lane >> 4;
    const int lim = (M - m0 < 128) ? (M - m0) : 128;

    // ---- As stage (2048 floats, 2 float4/thread) ----
#pragma unroll
    for (int i = 0; i < 2; ++i) {
        int idx = tid + 256 * i;
        *(float4*)&As[idx * 4] = *(const float4*)&A[idx * 4];
    }

    // ---- np^T via MFMA, staging fused: global->cvt->{MFMA + ds_write ins} ----
    // wave w covers m = w*32 + mt*16 + c, mt in {0,1}; (kb,q) covers all 128 k.
    const int r0 = w * 32 + c;            // local row, mt=0
    const int r1 = r0 + 16;               // local row, mt=1
    const bool v0 = r0 < lim, v1 = r1 < lim;
    const float* __restrict__ row0 = in + (size_t)(m0 + r0) * 128;
    const float* __restrict__ row1 = in + (size_t)(m0 + r1) * 128;

    f32x4 acc[2][8];
#pragma unroll
    for (int mt = 0; mt < 2; ++mt)
#pragma unroll
        for (int ot = 0; ot < 8; ++ot) acc[mt][ot] = (f32x4){0.f, 0.f, 0.f, 0.f};
#pragma unroll
    for (int kb = 0; kb < 4; ++kb) {
        const int k0 = kb * 32 + q * 8;
        float4 a0 = make_float4(0.f, 0.f, 0.f, 0.f), a1 = a0, b0 = a0, b1 = a0;
        if (v0) { a0 = *(const float4*)&row0[k0]; a1 = *(const float4*)&row0[k0 + 4]; }
        if (v1) { b0 = *(const float4*)&row1[k0]; b1 = *(const float4*)&row1[k0 + 4]; }
        bf16x8 bv0 = pack8(a0, a1);
        bf16x8 bv1 = pack8(b0, b1);
        *(bf16x8*)&ins[r0 * 136 + k0] = bv0;   // ds_write_b128, pool-phase copy
        *(bf16x8*)&ins[r1 * 136 + k0] = bv1;
#pragma unroll
        for (int ot = 0; ot < 8; ++ot) {
            bf16x8 av = *(const bf16x8*)(w1b + (ot * 16 + c) * 128 + k0);
            acc[0][ot] = __builtin_amdgcn_mfma_f32_16x16x32_bf16(av, bv0, acc[0][ot], 0, 0, 0);
            acc[1][ot] = __builtin_amdgcn_mfma_f32_16x16x32_bf16(av, bv1, acc[1][ot], 0, 0, 0);
        }
    }
    // acc[mt][ot][r] = np[m = w*32 + mt*16 + c][o = ot*16 + q*4 + r]
    __syncthreads();   // ins + As complete

    // ---- per-lane w2 quads, pre-scaled by 0.5 (relu-split) ----
    f32x4 w2q[8];
#pragma unroll
    for (int ot = 0; ot < 8; ++ot) {
        f32x4 wv = *(const f32x4*)&W2[ot * 16 + q * 4];
        w2q[ot] = wv * 0.5f;
    }

    // ---- sm = 0.5*Sum_o np*w2 per m-tile (b-invariant, hoisted) ----
    float sm0 = 0.f, sm1 = 0.f;
#pragma unroll
    for (int ot = 0; ot < 8; ++ot)
#pragma unroll
        for (int r = 0; r < 4; ++r) {
            sm0 += acc[0][ot][r] * w2q[ot][r];
            sm1 += acc[1][ot][r] * w2q[ot][r];
        }

    // ---- scores: s(b,m) = sm + 0.5*Sum_o |np+A|*w2 (per-b const dropped) ----
#pragma unroll
    for (int b = 0; b < 16; ++b) {
        float sa0 = sm0, sa1 = sm1;
#pragma unroll
        for (int ot = 0; ot < 8; ++ot) {
            f32x4 aq = *(f32x4*)&As[b * 128 + ot * 16 + q * 4];  // 16-lane broadcast
#pragma unroll
            for (int r = 0; r < 4; ++r) {
                sa0 += fabsf(acc[0][ot][r] + aq[r]) * w2q[ot][r];  // abs = free modifier
                sa1 += fabsf(acc[1][ot][r] + aq[r]) * w2q[ot][r];
            }
        }
        sa0 += __shfl_xor(sa0, 16, 64);
        sa0 += __shfl_xor(sa0, 32, 64);
        sa1 += __shfl_xor(sa1, 16, 64);
        sa1 += __shfl_xor(sa1, 32, 64);
        if (q == (b & 3)) {
            pb[b * 136 + r0] = (ushort)f2bs(v0 ? __expf(sa0) : 0.f);
            pb[b * 136 + r1] = (ushort)f2bs(v1 ? __expf(sa1) : 0.f);
        }
    }
    __syncthreads();

    // ---- pool via MFMA: D = P[16b x 128m] . in[128m x 128d]; wave owns 32 d ----
    f32x4 pd[2];
    pd[0] = (f32x4){0.f, 0.f, 0.f, 0.f};
    pd[1] = (f32x4){0.f, 0.f, 0.f, 0.f};
#pragma unroll
    for (int ks = 0; ks < 4; ++ks) {
        bf16x8 pf = *(const bf16x8*)&pb[c * 136 + ks * 32 + q * 8];  // A-frag P[b=c][k]
#pragma unroll
        for (int t = 0; t < 2; ++t) {
            const int dloc = w * 32 + t * 16 + c;
            bf16x8 bf;
#pragma unroll
            for (int j = 0; j < 8; ++j)
                bf[j] = (short)ins[(ks * 32 + q * 8 + j) * 136 + dloc];
            pd[t] = __builtin_amdgcn_mfma_f32_16x16x32_bf16(pf, bf, pd[t], 0, 0, 0);
        }
    }
    // pd[t][r] = pool[b = q*4+r][d = w*32 + t*16 + c]
#pragma unroll
    for (int t = 0; t < 2; ++t)
#pragma unroll
        for (int r = 0; r < 4; ++r)
            pacc[((size_t)bid * 16 + q * 4 + r) * 128 + w * 32 + t * 16 + c] =
                (ushort)f2bs(pd[t][r]);

    // ---- block lsum from pb: thread (b = tid>>4, jj = tid&15) covers 8 m ----
    {
        const int bb = tid >> 4, jj = tid & 15;
        const ushort* pr = &pb[bb * 136 + jj * 8];
        float part = 0.f;
#pragma unroll
        for (int j2 = 0; j2 < 8; ++j2) part += bs2f(pr[j2]);
#pragma unroll
        for (int off = 1; off < 16; off <<= 1) part += __shfl_xor(part, off, 64);
        if (jj == 0) lsum_g[bid * 16 + bb] = part;
    }
}

__global__ __launch_bounds__(1024) void kC2(
    const float* __restrict__ lsum_g, const ushort* __restrict__ pacc,
    float* __restrict__ out, int nb) {
    const int b = blockIdx.x;                 // 16 blocks x 1024 threads
    const int tid = threadIdx.x;
    const int d = tid & 127, h = tid >> 7;    // 8-way split over blocks
    __shared__ float reda[8 * 128];
    __shared__ float lred;

    float ac = 0.f;
    for (int blk = h; blk < nb; blk += 8)
        ac += bs2f(pacc[((size_t)blk * 16 + b) * 128 + d]);
    reda[h * 128 + d] = ac;

    if (tid < 64) {
        float ls = 0.f;
        for (int i = tid; i < nb; i += 64) ls += lsum_g[(size_t)i * 16 + b];
#pragma unroll
        for (int off = 1; off < 64; off <<= 1) ls += __shfl_xor(ls, off, 64);
        if (tid == 0) lred = ls;
    }
    __syncthreads();
    if (h == 0) {
        float a = 0.f;
#pragma unroll
        for (int i = 0; i < 8; ++i) a += reda[i * 128 + d];
        out[b * 128 + d] = a / lred;
    }
}

extern "C" void kernel_launch(void* const* d_in, const int* in_sizes, int n_in,
                              void* d_out, int out_size, void* d_ws, size_t ws_size,
                              hipStream_t stream) {
    const float* xx = (const float*)d_in[0];
    const float* in = (const float*)d_in[1];
    // d_in[2] = adj, unused
    const float* W1 = (const float*)d_in[3];
    const float* W2 = (const float*)d_in[4];
    float* out = (float*)d_out;

    const int M = in_sizes[1] / 128;
    const int nb = (M + 127) / 128;

    float* ws = (float*)d_ws;
    float* A      = ws;                               // 2048 floats
    float* lsum_g = A + 2048;                         // nb*16
    ushort* w1b   = (ushort*)(lsum_g + (size_t)nb * 16);  // 16384 bf16
    ushort* pacc  = w1b + 16384;                      // nb*16*128 bf16 (~3.2 MB)

    kA  <<<72, 256, 0, stream>>>(W1, xx, w1b, A);
    kB  <<<nb, 256, 0, stream>>>(in, w1b, W2, A, lsum_g, pacc, M);
    kC2 <<<16, 1024, 0, stream>>>(lsum_g, pacc, out, nb);
}

// Round 8
// 137.563 us; speedup vs baseline: 1.5650x; 1.1644x over previous
//
#include <hip/hip_runtime.h>
#include <hip/hip_bf16.h>
#include <math.h>

// B=16, D=128, OUT=128, M runtime (100000).
// v9 = v7's kB (fused staging, 47us measured) + two fixes:
//   1. scores: 4 independent accumulator chains (even/odd ot x 2 m-tiles),
//      chain depth 64 -> 32 (fp chains can't be compiler-reassociated; v7
//      latency budget showed ~47us vs ~10us compute+mem floor = stall-bound).
//      W2 loads hoisted above the barrier.
//   2. tail reverted to v1's proven kC1(256 blk)+kFin: v7's 16-block kC2
//      ran on 16 CUs and cost ~+20us vs kC1+kFin (rest: 107 vs 87us).
// Carried: fused staging (global->cvt->MFMA + ds_write), relu-split scores
//   (verified v2-v7), plain bf16 pacc stores (atomics abandoned: v5/v6 +54us).

typedef __attribute__((ext_vector_type(8))) short bf16x8;
typedef __attribute__((ext_vector_type(4))) float f32x4;

__device__ __forceinline__ short f2bs(float f) {
    __hip_bfloat16 h = __float2bfloat16(f);
    return *reinterpret_cast<short*>(&h);
}
__device__ __forceinline__ float bs2f(ushort u) {
    union { unsigned int i; float f; } v; v.i = ((unsigned)u) << 16; return v.f;
}
__device__ __forceinline__ bf16x8 pack8(float4 a, float4 b) {
    bf16x8 r;
    r[0] = f2bs(a.x); r[1] = f2bs(a.y); r[2] = f2bs(a.z); r[3] = f2bs(a.w);
    r[4] = f2bs(b.x); r[5] = f2bs(b.y); r[6] = f2bs(b.z); r[7] = f2bs(b.w);
    return r;
}

__global__ __launch_bounds__(256) void kA(const float* __restrict__ W1,
                                          const float* __restrict__ xx,
                                          ushort* __restrict__ w1b,
                                          float* __restrict__ A) {
    const int bi = blockIdx.x, t = threadIdx.x;
    if (bi < 64) {
        int idx = bi * 256 + t;              // 16384 = 128o * 128d
        int o = idx >> 7, d = idx & 127;
        w1b[idx] = (ushort)f2bs(W1[o * 256 + 128 + d]);
        return;
    }
    __shared__ float xxs[16 * 132];
    __shared__ float w1s[16 * 132];
    const int og0 = (bi - 64) * 16;
#pragma unroll
    for (int i = 0; i < 2; ++i) {
        int idx = t + 256 * i;               // 512 float4 = 16 rows * 32
        int r = idx >> 5, c4 = (idx & 31) << 2;
        *(float4*)&xxs[r * 132 + c4] = *(const float4*)&xx[r * 128 + c4];
        *(float4*)&w1s[r * 132 + c4] = *(const float4*)&W1[(og0 + r) * 256 + c4];
    }
    __syncthreads();
    const int ol = t >> 4, b = t & 15;
    float acc = 0.f;
#pragma unroll
    for (int d4 = 0; d4 < 32; ++d4) {
        float4 xv = *(float4*)&xxs[b * 132 + d4 * 4];
        float4 wv = *(float4*)&w1s[ol * 132 + d4 * 4];
        acc += xv.x * wv.x + xv.y * wv.y + xv.z * wv.z + xv.w * wv.w;
    }
    A[b * 128 + og0 + ol] = acc;
}

__global__ __launch_bounds__(256, 3) void kB(
    const float* __restrict__ in, const ushort* __restrict__ w1b,
    const float* __restrict__ W2, const float* __restrict__ A,
    float* __restrict__ lsum_g, ushort* __restrict__ pacc, int M) {
    __shared__ ushort ins[128 * 136];  // bf16 in-tile [m][d]
    __shared__ float As[16 * 128];     // A[b][o]
    __shared__ ushort pb[16 * 136];    // p bf16 [b][m(128)+pad]

    const int tid = threadIdx.x, bid = blockIdx.x;
    const int m0 = bid * 128;
    const int w = tid >> 6, lane = tid & 63;
    const int c = lane & 15, q = lane >> 4;
    const int lim = (M - m0 < 128) ? (M - m0) : 128;

    // ---- As stage (2048 floats, 2 float4/thread) ----
#pragma unroll
    for (int i = 0; i < 2; ++i) {
        int idx = tid + 256 * i;
        *(float4*)&As[idx * 4] = *(const float4*)&A[idx * 4];
    }

    // ---- np^T via MFMA, staging fused: global->cvt->{MFMA + ds_write ins} ----
    // wave w covers m = w*32 + mt*16 + c, mt in {0,1}; (kb,q) covers all 128 k.
    const int r0 = w * 32 + c;            // local row, mt=0
    const int r1 = r0 + 16;               // local row, mt=1
    const bool v0 = r0 < lim, v1 = r1 < lim;
    const float* __restrict__ row0 = in + (size_t)(m0 + r0) * 128;
    const float* __restrict__ row1 = in + (size_t)(m0 + r1) * 128;

    f32x4 acc[2][8];
#pragma unroll
    for (int mt = 0; mt < 2; ++mt)
#pragma unroll
        for (int ot = 0; ot < 8; ++ot) acc[mt][ot] = (f32x4){0.f, 0.f, 0.f, 0.f};
#pragma unroll
    for (int kb = 0; kb < 4; ++kb) {
        const int k0 = kb * 32 + q * 8;
        float4 a0 = make_float4(0.f, 0.f, 0.f, 0.f), a1 = a0, b0 = a0, b1 = a0;
        if (v0) { a0 = *(const float4*)&row0[k0]; a1 = *(const float4*)&row0[k0 + 4]; }
        if (v1) { b0 = *(const float4*)&row1[k0]; b1 = *(const float4*)&row1[k0 + 4]; }
        bf16x8 bv0 = pack8(a0, a1);
        bf16x8 bv1 = pack8(b0, b1);
        *(bf16x8*)&ins[r0 * 136 + k0] = bv0;   // ds_write_b128, pool-phase copy
        *(bf16x8*)&ins[r1 * 136 + k0] = bv1;
#pragma unroll
        for (int ot = 0; ot < 8; ++ot) {
            bf16x8 av = *(const bf16x8*)(w1b + (ot * 16 + c) * 128 + k0);
            acc[0][ot] = __builtin_amdgcn_mfma_f32_16x16x32_bf16(av, bv0, acc[0][ot], 0, 0, 0);
            acc[1][ot] = __builtin_amdgcn_mfma_f32_16x16x32_bf16(av, bv1, acc[1][ot], 0, 0, 0);
        }
    }
    // acc[mt][ot][r] = np[m = w*32 + mt*16 + c][o = ot*16 + q*4 + r]

    // ---- per-lane w2 quads, pre-scaled by 0.5 (hoisted above barrier) ----
    f32x4 w2q[8];
#pragma unroll
    for (int ot = 0; ot < 8; ++ot) {
        f32x4 wv = *(const f32x4*)&W2[ot * 16 + q * 4];
        w2q[ot] = wv * 0.5f;
    }
    __syncthreads();   // ins + As complete

    // ---- sm = 0.5*Sum_o np*w2 per m-tile (b-invariant, hoisted) ----
    float sm0 = 0.f, sm1 = 0.f;
#pragma unroll
    for (int ot = 0; ot < 8; ++ot)
#pragma unroll
        for (int r = 0; r < 4; ++r) {
            sm0 += acc[0][ot][r] * w2q[ot][r];
            sm1 += acc[1][ot][r] * w2q[ot][r];
        }

    // ---- scores: s(b,m) = sm + 0.5*Sum_o |np+A|*w2 (per-b const dropped) ----
    // 4 independent chains (even/odd ot x 2 mt): depth 64 -> 32 (latency fix)
#pragma unroll
    for (int b = 0; b < 16; ++b) {
        float sa0 = sm0, sa1 = sm1, sb0 = 0.f, sb1 = 0.f;
#pragma unroll
        for (int ot = 0; ot < 8; ot += 2) {
            f32x4 aq0 = *(f32x4*)&As[b * 128 + ot * 16 + q * 4];        // broadcast
            f32x4 aq1 = *(f32x4*)&As[b * 128 + (ot + 1) * 16 + q * 4];
#pragma unroll
            for (int r = 0; r < 4; ++r) {
                sa0 += fabsf(acc[0][ot][r]     + aq0[r]) * w2q[ot][r];
                sa1 += fabsf(acc[1][ot][r]     + aq0[r]) * w2q[ot][r];
                sb0 += fabsf(acc[0][ot + 1][r] + aq1[r]) * w2q[ot + 1][r];
                sb1 += fabsf(acc[1][ot + 1][r] + aq1[r]) * w2q[ot + 1][r];
            }
        }
        float s0 = sa0 + sb0, s1 = sa1 + sb1;
        s0 += __shfl_xor(s0, 16, 64);
        s0 += __shfl_xor(s0, 32, 64);
        s1 += __shfl_xor(s1, 16, 64);
        s1 += __shfl_xor(s1, 32, 64);
        if (q == (b & 3)) {
            pb[b * 136 + r0] = (ushort)f2bs(v0 ? __expf(s0) : 0.f);
            pb[b * 136 + r1] = (ushort)f2bs(v1 ? __expf(s1) : 0.f);
        }
    }
    __syncthreads();

    // ---- pool via MFMA: D = P[16b x 128m] . in[128m x 128d]; wave owns 32 d ----
    f32x4 pd[2];
    pd[0] = (f32x4){0.f, 0.f, 0.f, 0.f};
    pd[1] = (f32x4){0.f, 0.f, 0.f, 0.f};
#pragma unroll
    for (int ks = 0; ks < 4; ++ks) {
        bf16x8 pf = *(const bf16x8*)&pb[c * 136 + ks * 32 + q * 8];  // A-frag P[b=c][k]
#pragma unroll
        for (int t = 0; t < 2; ++t) {
            const int dloc = w * 32 + t * 16 + c;
            bf16x8 bf;
#pragma unroll
            for (int j = 0; j < 8; ++j)
                bf[j] = (short)ins[(ks * 32 + q * 8 + j) * 136 + dloc];
            pd[t] = __builtin_amdgcn_mfma_f32_16x16x32_bf16(pf, bf, pd[t], 0, 0, 0);
        }
    }
    // pd[t][r] = pool[b = q*4+r][d = w*32 + t*16 + c]
#pragma unroll
    for (int t = 0; t < 2; ++t)
#pragma unroll
        for (int r = 0; r < 4; ++r)
            pacc[((size_t)bid * 16 + q * 4 + r) * 128 + w * 32 + t * 16 + c] =
                (ushort)f2bs(pd[t][r]);

    // ---- block lsum from pb: thread (b = tid>>4, jj = tid&15) covers 8 m ----
    {
        const int bb = tid >> 4, jj = tid & 15;
        const ushort* pr = &pb[bb * 136 + jj * 8];
        float part = 0.f;
#pragma unroll
        for (int j2 = 0; j2 < 8; ++j2) part += bs2f(pr[j2]);
#pragma unroll
        for (int off = 1; off < 16; off <<= 1) part += __shfl_xor(part, off, 64);
        if (jj == 0) lsum_g[bid * 16 + bb] = part;
    }
}

__global__ __launch_bounds__(256) void kC1(
    const float* __restrict__ lsum_g, const ushort* __restrict__ pacc,
    float* __restrict__ pacc2, float* __restrict__ lsum2, int nb) {
    const int b = blockIdx.x >> 4, s = blockIdx.x & 15;
    const int t = threadIdx.x;
    __shared__ float reda[2 * 128];
    __shared__ float redl[2];
    const int cs = (nb + 15) >> 4;
    const int blk0 = s * cs;
    int blk1 = blk0 + cs; if (blk1 > nb) blk1 = nb;
    const int dd = t & 127, h = t >> 7;
    float ac = 0.f, ls = 0.f;
    for (int blk = blk0 + h; blk < blk1; blk += 2) {
        ac += bs2f(pacc[((size_t)blk * 16 + b) * 128 + dd]);
        ls += lsum_g[blk * 16 + b];
    }
    reda[h * 128 + dd] = ac;
    if (dd == 0) redl[h] = ls;
    __syncthreads();
    if (h == 0) {
        pacc2[((size_t)s * 16 + b) * 128 + dd] = reda[dd] + reda[128 + dd];
        if (dd == 0) lsum2[s * 16 + b] = redl[0] + redl[1];
    }
}

__global__ void kFin(const float* __restrict__ pacc2, const float* __restrict__ lsum2,
                     float* __restrict__ out) {
    const int b = blockIdx.x, t = threadIdx.x;   // 16 blocks x 128 threads
    float ac = 0.f, ls = 0.f;
#pragma unroll
    for (int s = 0; s < 16; ++s) {
        ac += pacc2[((size_t)s * 16 + b) * 128 + t];
        ls += lsum2[s * 16 + b];
    }
    out[b * 128 + t] = ac / ls;
}

extern "C" void kernel_launch(void* const* d_in, const int* in_sizes, int n_in,
                              void* d_out, int out_size, void* d_ws, size_t ws_size,
                              hipStream_t stream) {
    const float* xx = (const float*)d_in[0];
    const float* in = (const float*)d_in[1];
    // d_in[2] = adj, unused
    const float* W1 = (const float*)d_in[3];
    const float* W2 = (const float*)d_in[4];
    float* out = (float*)d_out;

    const int M = in_sizes[1] / 128;
    const int nb = (M + 127) / 128;

    float* ws = (float*)d_ws;
    float* A      = ws;                             // 2048
    float* lsum_g = A + 2048;                       // nb*16
    float* pacc2  = lsum_g + (size_t)nb * 16;       // 256*128
    float* lsum2  = pacc2 + 256 * 128;              // 256
    ushort* w1b   = (ushort*)(lsum2 + 256);         // 16384
    ushort* pacc  = w1b + 16384;                    // nb*16*128 bf16 (~3.2 MB)

    kA  <<<72, 256, 0, stream>>>(W1, xx, w1b, A);
    kB  <<<nb, 256, 0, stream>>>(in, w1b, W2, A, lsum_g, pacc, M);
    kC1 <<<256, 256, 0, stream>>>(lsum_g, pacc, pacc2, lsum2, nb);
    kFin<<<16, 128, 0, stream>>>(pacc2, lsum2, out);
}